// Round 4
// baseline (75.328 us; speedup 1.0000x reference)
//
#include <hip/hip_runtime.h>

// Problem constants
#define IMGX   144
#define PATCH  4
#define NPS    36      // patches per side
#define NTOKB  1296    // tokens per batch
#define ED     16      // embedding dim
#define NTOK   5184    // total tokens
#define RPW    4       // query rows per block (shared by all 4 waves)
#define BPB    324     // blocks per batch = 1296/RPW
#define NCHUNK 21      // chunks of 64 tokens per batch (last has 16 valid)
#define PREP_BLOCKS 21

// Module-scope scratch (load-time allocated; capture-safe, no d_ws).
__device__ float  g_partial[PREP_BLOCKS];   // per-block input maxima
__device__ float  g_norms[NTOK];            // per-token squared norms (raw x)
__device__ float2 g_xt[4 * 8 * NTOKB];      // TRANSPOSED tokens: [b][d2][j],
                                            // float2 = dims (2*d2, 2*d2+1).
                                            // Purpose: j-loads in attn become
                                            // lane-stride-8B coalesced dwordx2
                                            // (vs 64B-stride dwordx4 = 64
                                            // lines/inst in rounds 2/3).

// Kernel 1: per-token squared norms + transpose + per-block max.
__global__ __launch_bounds__(256) void prep_kernel(const float* __restrict__ x) {
    __shared__ float wmax[4];
    const int tid = threadIdx.x;
    const int t = blockIdx.x * 256 + tid;
    float m = 0.0f;
    if (t < NTOK) {
        const float4* p = (const float4*)(x + t * ED);
        float4 a = p[0], bq = p[1], cq = p[2], dq = p[3];
        float ns = 0.0f;
        ns = fmaf(a.x, a.x, ns);   ns = fmaf(a.y, a.y, ns);
        ns = fmaf(a.z, a.z, ns);   ns = fmaf(a.w, a.w, ns);
        ns = fmaf(bq.x, bq.x, ns); ns = fmaf(bq.y, bq.y, ns);
        ns = fmaf(bq.z, bq.z, ns); ns = fmaf(bq.w, bq.w, ns);
        ns = fmaf(cq.x, cq.x, ns); ns = fmaf(cq.y, cq.y, ns);
        ns = fmaf(cq.z, cq.z, ns); ns = fmaf(cq.w, cq.w, ns);
        ns = fmaf(dq.x, dq.x, ns); ns = fmaf(dq.y, dq.y, ns);
        ns = fmaf(dq.z, dq.z, ns); ns = fmaf(dq.w, dq.w, ns);
        g_norms[t] = ns;

        // Transposed copy: plane d2 holds dims (2d2, 2d2+1) for all tokens.
        // Across threads jb is consecutive -> each plane-store is coalesced.
        const int bb = t / NTOKB;
        const int jb = t - bb * NTOKB;
        float2* xt = g_xt + bb * (8 * NTOKB) + jb;
        xt[0 * NTOKB] = make_float2(a.x, a.y);
        xt[1 * NTOKB] = make_float2(a.z, a.w);
        xt[2 * NTOKB] = make_float2(bq.x, bq.y);
        xt[3 * NTOKB] = make_float2(bq.z, bq.w);
        xt[4 * NTOKB] = make_float2(cq.x, cq.y);
        xt[5 * NTOKB] = make_float2(cq.z, cq.w);
        xt[6 * NTOKB] = make_float2(dq.x, dq.y);
        xt[7 * NTOKB] = make_float2(dq.z, dq.w);

        // x >= 0 (uniform[0,1)), so 0-init max is safe
        m = fmaxf(fmaxf(fmaxf(a.x, a.y), fmaxf(a.z, a.w)),
                  fmaxf(fmaxf(fmaxf(bq.x, bq.y), fmaxf(bq.z, bq.w)),
                        fmaxf(fmaxf(fmaxf(cq.x, cq.y), fmaxf(cq.z, cq.w)),
                              fmaxf(fmaxf(dq.x, dq.y), fmaxf(dq.z, dq.w)))));
    }
#pragma unroll
    for (int s = 32; s; s >>= 1) m = fmaxf(m, __shfl_xor(m, s));
    if ((tid & 63) == 0) wmax[tid >> 6] = m;
    __syncthreads();
    if (tid == 0) {
        g_partial[blockIdx.x] = fmaxf(fmaxf(wmax[0], wmax[1]), fmaxf(wmax[2], wmax[3]));
    }
}

// Kernel 2: fused attention + merging.
// 1296 blocks x 256 threads; 4 waves share the block's 4 query rows, split the
// 21 j-chunks as c === w (mod 4). No LDS / no barriers in the main loop.
// j-tokens come from the TRANSPOSED g_xt: 8 coalesced dwordx2 per chunk
// (8 lines/inst) + 1 coalesced norm dword, replacing rounds-2/3's 17
// address-divergent loads (64 lines/inst) that were the ~21us wall.
//
// Math: logit l_ij = s*(2*dot - n_j) - s*n_i, s = 1/(16*xmax^2). Row-constant
// cancels in softmax -> p = exp2(c2*dot - cf*n_j), c2 = 2s*log2e folded into
// the query registers, cf = s*log2e. p <= e^2, denom >= 1: no online softmax.
// Per-row dot chains keep dim-ascending fmaf order (numerics identical to R3).
__global__ __launch_bounds__(256, 2) void attn_kernel(const float* __restrict__ x,
                                                      float* __restrict__ out) {
    __shared__ float redo[4][64];  // per-wave output partials (idx = r*16+d)
    __shared__ float redd[4][4];   // per-wave denominator partials (per row)

    const int tid  = threadIdx.x;
    const int lane = tid & 63;
    const int w    = tid >> 6;            // wave id -> chunk residue class
    const int blk  = blockIdx.x;          // 0..1295
    const int b    = blk / BPB;
    const int i0   = (blk - b * BPB) * RPW;

    const float*  __restrict__ xb    = x + b * (NTOKB * ED);
    const float*  __restrict__ norms = g_norms + b * NTOKB;
    const float2* __restrict__ xt    = g_xt + b * (8 * NTOKB);

    // Global max from the 21 prep partials (full 64-lane butterfly).
    float pm = (lane < PREP_BLOCKS) ? g_partial[lane] : 0.0f;
#pragma unroll
    for (int sh = 32; sh; sh >>= 1) pm = fmaxf(pm, __shfl_xor(pm, sh));
    const float xmax = pm;
    const float s  = 1.0f / (16.0f * xmax * xmax);
    const float c2 = 2.0f * s * 1.4426950408889634f;  // 2s*log2(e) -> queries
    const float cf = s * 1.4426950408889634f;         // s*log2(e)  -> n_j

    // 4 query rows, pre-scaled by c2, packed as float2 pairs (dims 2h, 2h+1).
    float2 ti[4][8];
#pragma unroll
    for (int r = 0; r < 4; r++) {
        const float4* p = (const float4*)(xb + (i0 + r) * ED);
#pragma unroll
        for (int q = 0; q < 4; q++) {
            const float4 a = p[q];
            ti[r][2 * q + 0] = make_float2(a.x * c2, a.y * c2);
            ti[r][2 * q + 1] = make_float2(a.z * c2, a.w * c2);
        }
    }

    float2 o[4][8];
#pragma unroll
    for (int r = 0; r < 4; r++)
#pragma unroll
        for (int h = 0; h < 8; h++) { o[r][h].x = 0.f; o[r][h].y = 0.f; }
    float den0 = 0.f, den1 = 0.f, den2 = 0.f, den3 = 0.f;

    // Prologue: load chunk w (chunks 0..3 are fully valid).
    float2 cur[8];
    float  njc;
    {
        const int j = w * 64 + lane;
#pragma unroll
        for (int h = 0; h < 8; h++) cur[h] = xt[h * NTOKB + j];
        njc = norms[j];
    }

    for (int t = 0; ; t++) {
        const int c    = w + 4 * t;       // current chunk (wave-uniform)
        const int cnx  = c + 4;           // next chunk for this wave
        const bool more = (cnx < NCHUNK); // wave-uniform branch

        // Prefetch next chunk; vmcnt wait lands after this iteration's compute.
        float2 nxt[8];
        float  njn = 0.f;
        if (more) {
            const int j  = cnx * 64 + lane;
            const int jc = (j < NTOKB) ? j : 0;  // clamp (chunk 20, lanes>=16)
#pragma unroll
            for (int h = 0; h < 8; h++) nxt[h] = xt[h * NTOKB + jc];
            njn = norms[jc];
        }

        const bool valid = (c * 64 + lane) < NTOKB;  // false only in chunk 20

        float d0 = 0.f, d1 = 0.f, d2 = 0.f, d3 = 0.f;
#pragma unroll
        for (int h = 0; h < 8; h++) {
            const float2 t2 = cur[h];
            d0 = fmaf(ti[0][h].x, t2.x, d0); d0 = fmaf(ti[0][h].y, t2.y, d0);
            d1 = fmaf(ti[1][h].x, t2.x, d1); d1 = fmaf(ti[1][h].y, t2.y, d1);
            d2 = fmaf(ti[2][h].x, t2.x, d2); d2 = fmaf(ti[2][h].y, t2.y, d2);
            d3 = fmaf(ti[3][h].x, t2.x, d3); d3 = fmaf(ti[3][h].y, t2.y, d3);
        }

        const float cc = cf * njc;
        float e0 = __builtin_amdgcn_exp2f(d0 - cc);
        float e1 = __builtin_amdgcn_exp2f(d1 - cc);
        float e2 = __builtin_amdgcn_exp2f(d2 - cc);
        float e3 = __builtin_amdgcn_exp2f(d3 - cc);
        e0 = valid ? e0 : 0.f;
        e1 = valid ? e1 : 0.f;
        e2 = valid ? e2 : 0.f;
        e3 = valid ? e3 : 0.f;
        den0 += e0; den1 += e1; den2 += e2; den3 += e3;
#pragma unroll
        for (int h = 0; h < 8; h++) {
            const float2 t2 = cur[h];
            o[0][h].x = fmaf(e0, t2.x, o[0][h].x); o[0][h].y = fmaf(e0, t2.y, o[0][h].y);
            o[1][h].x = fmaf(e1, t2.x, o[1][h].x); o[1][h].y = fmaf(e1, t2.y, o[1][h].y);
            o[2][h].x = fmaf(e2, t2.x, o[2][h].x); o[2][h].y = fmaf(e2, t2.y, o[2][h].y);
            o[3][h].x = fmaf(e3, t2.x, o[3][h].x); o[3][h].y = fmaf(e3, t2.y, o[3][h].y);
        }

        if (!more) break;
#pragma unroll
        for (int h = 0; h < 8; h++) cur[h] = nxt[h];
        njc = njn;
    }

    // Denominators: plain 64-lane butterfly (4 values).
#pragma unroll
    for (int sh = 32; sh; sh >>= 1) {
        den0 += __shfl_xor(den0, sh);
        den1 += __shfl_xor(den1, sh);
        den2 += __shfl_xor(den2, sh);
        den3 += __shfl_xor(den3, sh);
    }

    // Split-butterfly over the 64 flattened partials (idx = r*16 + d, with
    // d = 2h + comp). Six stages, LITERAL masks; component select folds to a
    // register lvalue after the literal-bound unroll. Lane L ends with idx=L.
#define CMP2(v, c) ((c) ? (v).y : (v).x)
#define V(n) CMP2(o[(n) >> 4][((n) >> 1) & 7], (n) & 1)
#define BSTAGE(M)                                                   \
    {                                                               \
        const bool hi = (lane & (M)) != 0;                          \
        _Pragma("unroll")                                           \
        for (int k = 0; k < (M); k++) {                             \
            const float give = hi ? V(k) : V(k + (M));              \
            const float got  = __shfl_xor(give, (M));               \
            V(k) = (hi ? V(k + (M)) : V(k)) + got;                  \
        }                                                           \
    }
    BSTAGE(32) BSTAGE(16) BSTAGE(8) BSTAGE(4) BSTAGE(2) BSTAGE(1)

    redo[w][lane] = V(0);
    if (lane == 0) {
        redd[w][0] = den0; redd[w][1] = den1; redd[w][2] = den2; redd[w][3] = den3;
    }
    __syncthreads();

    if (w == 0) {
        const float v = redo[0][lane] + redo[1][lane] + redo[2][lane] + redo[3][lane];
        const int r = lane >> 4;
        const int d = lane & 15;
        const float den = redd[0][r] + redd[1][r] + redd[2][r] + redd[3][r];
        const float val = v / den;

        // Merging permutation: row i -> patch (by,bx); d=(ky,kx) -> pixel.
        const int i  = i0 + r;
        const int by = i / NPS;
        const int bx = i - by * NPS;
        out[b * (IMGX * IMGX) + (by * PATCH + (d >> 2)) * IMGX + bx * PATCH + (d & 3)] = val;
    }
#undef V
#undef CMP2
#undef BSTAGE
}

extern "C" void kernel_launch(void* const* d_in, const int* in_sizes, int n_in,
                              void* d_out, int out_size, void* d_ws, size_t ws_size,
                              hipStream_t stream) {
    const float* x = (const float*)d_in[0];  // f32 (4,1,144,144)
    float* out = (float*)d_out;              // f32 (4,1,144,144)
    (void)d_ws; (void)ws_size;

    hipLaunchKernelGGL(prep_kernel, dim3(PREP_BLOCKS), dim3(256), 0, stream, x);
    hipLaunchKernelGGL(attn_kernel, dim3(NTOKB), dim3(256), 0, stream, x, out);
}

// Round 5
// 74.236 us; speedup vs baseline: 1.0147x; 1.0147x over previous
//
#include <hip/hip_runtime.h>

// Problem constants
#define IMGX   144
#define PATCH  4
#define NPS    36      // patches per side
#define NTOKB  1296    // tokens per batch
#define NTP    1536    // PADDED tokens per batch (24 chunks of 64)
#define ED     16      // embedding dim
#define NTOK   5184    // total real tokens
#define RPW    4       // query rows per block (shared by all 4 waves)
#define BPB    324     // blocks per batch = 1296/RPW
#define PREP_BLOCKS 24 // 6144 threads = 5184 real + 960 pad tokens

// Module-scope scratch (load-time allocated; capture-safe, no d_ws).
__device__ float  g_partial[PREP_BLOCKS];  // per-block input maxima
__device__ float  g_norms[4 * NTP];        // per-token ||x||^2; pads = 1e9
__device__ float2 g_xt[4 * 8 * NTP];       // transposed tokens [b][d2][j]; pads = 0
// Pad trick: exp2(c2*0 - cf*1e9) == 0.0f exactly, so pad tokens contribute
// +0.0 to denom and output -> the attn main loop needs NO masking at all.

// Kernel 1: squared norms + transpose + pad init + per-block max.
__global__ __launch_bounds__(256) void prep_kernel(const float* __restrict__ x) {
    __shared__ float wmax[4];
    const int tid = threadIdx.x;
    const int t = blockIdx.x * 256 + tid;
    float m = 0.0f;
    if (t < NTOK) {
        const float4* p = (const float4*)(x + t * ED);
        float4 a = p[0], bq = p[1], cq = p[2], dq = p[3];
        float ns = 0.0f;
        ns = fmaf(a.x, a.x, ns);   ns = fmaf(a.y, a.y, ns);
        ns = fmaf(a.z, a.z, ns);   ns = fmaf(a.w, a.w, ns);
        ns = fmaf(bq.x, bq.x, ns); ns = fmaf(bq.y, bq.y, ns);
        ns = fmaf(bq.z, bq.z, ns); ns = fmaf(bq.w, bq.w, ns);
        ns = fmaf(cq.x, cq.x, ns); ns = fmaf(cq.y, cq.y, ns);
        ns = fmaf(cq.z, cq.z, ns); ns = fmaf(cq.w, cq.w, ns);
        ns = fmaf(dq.x, dq.x, ns); ns = fmaf(dq.y, dq.y, ns);
        ns = fmaf(dq.z, dq.z, ns); ns = fmaf(dq.w, dq.w, ns);

        const int bb = t / NTOKB;
        const int jb = t - bb * NTOKB;
        g_norms[bb * NTP + jb] = ns;
        float2* xt = g_xt + bb * (8 * NTP) + jb;   // coalesced: jb consecutive
        xt[0 * NTP] = make_float2(a.x, a.y);
        xt[1 * NTP] = make_float2(a.z, a.w);
        xt[2 * NTP] = make_float2(bq.x, bq.y);
        xt[3 * NTP] = make_float2(bq.z, bq.w);
        xt[4 * NTP] = make_float2(cq.x, cq.y);
        xt[5 * NTP] = make_float2(cq.z, cq.w);
        xt[6 * NTP] = make_float2(dq.x, dq.y);
        xt[7 * NTP] = make_float2(dq.z, dq.w);

        // x >= 0 (uniform[0,1)), so 0-init max is safe
        m = fmaxf(fmaxf(fmaxf(a.x, a.y), fmaxf(a.z, a.w)),
                  fmaxf(fmaxf(fmaxf(bq.x, bq.y), fmaxf(bq.z, bq.w)),
                        fmaxf(fmaxf(fmaxf(cq.x, cq.y), fmaxf(cq.z, cq.w)),
                              fmaxf(fmaxf(dq.x, dq.y), fmaxf(dq.z, dq.w)))));
    } else {
        // Pad tokens: 960 = 4 batches x 240 (j in [1296,1536)).
        const int p  = t - NTOK;
        const int bb = p / 240;
        const int jb = NTOKB + (p - bb * 240);
        g_norms[bb * NTP + jb] = 1.0e9f;           // exp2(-cf*1e9) == 0
        float2* xt = g_xt + bb * (8 * NTP) + jb;
        const float2 z = make_float2(0.f, 0.f);
        xt[0 * NTP] = z; xt[1 * NTP] = z; xt[2 * NTP] = z; xt[3 * NTP] = z;
        xt[4 * NTP] = z; xt[5 * NTP] = z; xt[6 * NTP] = z; xt[7 * NTP] = z;
    }
#pragma unroll
    for (int s = 32; s; s >>= 1) m = fmaxf(m, __shfl_xor(m, s));
    if ((tid & 63) == 0) wmax[tid >> 6] = m;
    __syncthreads();
    if (tid == 0) {
        g_partial[blockIdx.x] = fmaxf(fmaxf(wmax[0], wmax[1]), fmaxf(wmax[2], wmax[3]));
    }
}

// Kernel 2: fused attention + merging.
// 1296 blocks x 256 threads; 4 waves share the block's 4 query rows and split
// the 24 padded chunks as c === w (mod 4): exactly 6 uniform chunks per wave,
// zero masking/branches. Coalesced transposed loads (8 dwordx2 + 1 dword per
// chunk), static 2-bank pipeline (loads one full chunk-compute ahead).
//
// OCCUPANCY PIN (round-5 fix): amdgpu_waves_per_eu(2,2) forces the register
// budget to 256 so the ~195-reg live set (ti 64 + o 64 + banks 32 + misc)
// CANNOT be spilled by the allocator chasing >2 waves/EU. Rounds 1-4 evidence:
// R1 allocated 92 VGPR for a >=160 live set (scratch-backed accumulator RMW),
// and R2-4's invariant ~21-25us across three different memory paths matches
// spilled-o[] scratch traffic, not VMEM/LDS behavior.
//
// Math: logit l_ij = s*(2*dot - n_j) - s*n_i, s = 1/(16*xmax^2). Row-constant
// cancels in softmax -> p = exp2(c2*dot - cf*n_j), c2 = 2s*log2e folded into
// the query registers, cf = s*log2e. p <= e^2, denom >= 1. fmaf chain order
// identical to R4 -> bit-identical numerics; pads add exactly +0.0.
__global__ __attribute__((amdgpu_waves_per_eu(2, 2)))
__launch_bounds__(256) void attn_kernel(const float* __restrict__ x,
                                        float* __restrict__ out) {
    __shared__ float redo[4][64];  // per-wave output partials (idx = r*16+d)
    __shared__ float redd[4][4];   // per-wave denominator partials (per row)

    const int tid  = threadIdx.x;
    const int lane = tid & 63;
    const int w    = tid >> 6;            // wave id -> chunk residue class
    const int blk  = blockIdx.x;          // 0..1295
    const int b    = blk / BPB;
    const int i0   = (blk - b * BPB) * RPW;

    const float*  __restrict__ xb = x + b * (NTOKB * ED);
    const float2* __restrict__ xw = g_xt + b * (8 * NTP) + (w * 64 + lane);
    const float*  __restrict__ nr = g_norms + b * NTP + (w * 64 + lane);

    // Global max from the 24 prep partials (full 64-lane butterfly).
    float pm = (lane < PREP_BLOCKS) ? g_partial[lane] : 0.0f;
#pragma unroll
    for (int sh = 32; sh; sh >>= 1) pm = fmaxf(pm, __shfl_xor(pm, sh));
    const float xmax = pm;
    const float s  = 1.0f / (16.0f * xmax * xmax);
    const float c2 = 2.0f * s * 1.4426950408889634f;  // 2s*log2(e) -> queries
    const float cf = s * 1.4426950408889634f;         // s*log2(e)  -> n_j

    // 4 query rows, pre-scaled by c2, packed as float2 pairs (dims 2h, 2h+1).
    float2 ti[4][8];
#pragma unroll
    for (int r = 0; r < 4; r++) {
        const float4* p = (const float4*)(xb + (i0 + r) * ED);
#pragma unroll
        for (int q = 0; q < 4; q++) {
            const float4 a = p[q];
            ti[r][2 * q + 0] = make_float2(a.x * c2, a.y * c2);
            ti[r][2 * q + 1] = make_float2(a.z * c2, a.w * c2);
        }
    }

    float2 o[4][8];
#pragma unroll
    for (int r = 0; r < 4; r++)
#pragma unroll
        for (int h = 0; h < 8; h++) { o[r][h].x = 0.f; o[r][h].y = 0.f; }
    float den0 = 0.f, den1 = 0.f, den2 = 0.f, den3 = 0.f;

    // Chunk t (t = 0..5) = tokens [w*64 + 256*t, +64): element offset 256*t
    // in the padded [b][plane][j] layout -- compile-time literal per stage.
    float2 bkA[8], bkB[8];
    float  njA, njB;

#define LOADX(BK, NJ, T)                                                 \
    {                                                                    \
        _Pragma("unroll")                                                \
        for (int h = 0; h < 8; h++) BK[h] = xw[h * NTP + 256 * (T)];     \
        NJ = nr[256 * (T)];                                              \
    }

#define CHUNK(BK, NJ)                                                            \
    {                                                                            \
        float d0 = 0.f, d1 = 0.f, d2 = 0.f, d3 = 0.f;                            \
        _Pragma("unroll")                                                        \
        for (int h = 0; h < 8; h++) {                                            \
            const float2 t2 = BK[h];                                             \
            d0 = fmaf(ti[0][h].x, t2.x, d0); d0 = fmaf(ti[0][h].y, t2.y, d0);    \
            d1 = fmaf(ti[1][h].x, t2.x, d1); d1 = fmaf(ti[1][h].y, t2.y, d1);    \
            d2 = fmaf(ti[2][h].x, t2.x, d2); d2 = fmaf(ti[2][h].y, t2.y, d2);    \
            d3 = fmaf(ti[3][h].x, t2.x, d3); d3 = fmaf(ti[3][h].y, t2.y, d3);    \
        }                                                                        \
        const float cc = cf * (NJ);                                              \
        const float e0 = __builtin_amdgcn_exp2f(d0 - cc);                        \
        const float e1 = __builtin_amdgcn_exp2f(d1 - cc);                        \
        const float e2 = __builtin_amdgcn_exp2f(d2 - cc);                        \
        const float e3 = __builtin_amdgcn_exp2f(d3 - cc);                        \
        den0 += e0; den1 += e1; den2 += e2; den3 += e3;                          \
        _Pragma("unroll")                                                        \
        for (int h = 0; h < 8; h++) {                                            \
            const float2 t2 = BK[h];                                             \
            o[0][h].x = fmaf(e0, t2.x, o[0][h].x); o[0][h].y = fmaf(e0, t2.y, o[0][h].y); \
            o[1][h].x = fmaf(e1, t2.x, o[1][h].x); o[1][h].y = fmaf(e1, t2.y, o[1][h].y); \
            o[2][h].x = fmaf(e2, t2.x, o[2][h].x); o[2][h].y = fmaf(e2, t2.y, o[2][h].y); \
            o[3][h].x = fmaf(e3, t2.x, o[3][h].x); o[3][h].y = fmaf(e3, t2.y, o[3][h].y); \
        }                                                                        \
    }

    // Static 2-bank pipeline: every load issues a full chunk-compute (~300cyc)
    // before its consumer; banks alternate, all names/indices compile-time.
    LOADX(bkA, njA, 0)
    LOADX(bkB, njB, 1)
    CHUNK(bkA, njA)
    LOADX(bkA, njA, 2)
    CHUNK(bkB, njB)
    LOADX(bkB, njB, 3)
    CHUNK(bkA, njA)
    LOADX(bkA, njA, 4)
    CHUNK(bkB, njB)
    LOADX(bkB, njB, 5)
    CHUNK(bkA, njA)
    CHUNK(bkB, njB)
#undef LOADX
#undef CHUNK

    // Denominators: plain 64-lane butterfly (4 values).
#pragma unroll
    for (int sh = 32; sh; sh >>= 1) {
        den0 += __shfl_xor(den0, sh);
        den1 += __shfl_xor(den1, sh);
        den2 += __shfl_xor(den2, sh);
        den3 += __shfl_xor(den3, sh);
    }

    // Split-butterfly over the 64 flattened partials (idx = r*16 + 2h + comp).
    // Six stages, LITERAL masks; component select folds to a register lvalue
    // after the literal-bound unroll. Lane L ends owning idx = L. (Proven R4.)
#define CMP2(v, c) ((c) ? (v).y : (v).x)
#define V(n) CMP2(o[(n) >> 4][((n) >> 1) & 7], (n) & 1)
#define BSTAGE(M)                                                   \
    {                                                               \
        const bool hi = (lane & (M)) != 0;                          \
        _Pragma("unroll")                                           \
        for (int k = 0; k < (M); k++) {                             \
            const float give = hi ? V(k) : V(k + (M));              \
            const float got  = __shfl_xor(give, (M));               \
            V(k) = (hi ? V(k + (M)) : V(k)) + got;                  \
        }                                                           \
    }
    BSTAGE(32) BSTAGE(16) BSTAGE(8) BSTAGE(4) BSTAGE(2) BSTAGE(1)

    redo[w][lane] = V(0);
    if (lane == 0) {
        redd[w][0] = den0; redd[w][1] = den1; redd[w][2] = den2; redd[w][3] = den3;
    }
    __syncthreads();

    if (w == 0) {
        const float v = redo[0][lane] + redo[1][lane] + redo[2][lane] + redo[3][lane];
        const int r = lane >> 4;
        const int d = lane & 15;
        const float den = redd[0][r] + redd[1][r] + redd[2][r] + redd[3][r];
        const float val = v / den;

        // Merging permutation: row i -> patch (by,bx); d=(ky,kx) -> pixel.
        const int i  = i0 + r;
        const int by = i / NPS;
        const int bx = i - by * NPS;
        out[b * (IMGX * IMGX) + (by * PATCH + (d >> 2)) * IMGX + bx * PATCH + (d & 3)] = val;
    }
#undef V
#undef CMP2
#undef BSTAGE
}

extern "C" void kernel_launch(void* const* d_in, const int* in_sizes, int n_in,
                              void* d_out, int out_size, void* d_ws, size_t ws_size,
                              hipStream_t stream) {
    const float* x = (const float*)d_in[0];  // f32 (4,1,144,144)
    float* out = (float*)d_out;              // f32 (4,1,144,144)
    (void)d_ws; (void)ws_size;

    hipLaunchKernelGGL(prep_kernel, dim3(PREP_BLOCKS), dim3(256), 0, stream, x);
    hipLaunchKernelGGL(attn_kernel, dim3(NTOKB), dim3(256), 0, stream, x, out);
}